// Round 14
// baseline (22.981 us; speedup 1.0000x reference)
//
#include <hip/hip_runtime.h>
#include <stdint.h>

// ACOLayer: reproduce JAX's sampling exactly.
//   u = jax.random.uniform(key(42), (32, 4096, 16), f32)
//   idx[b,i,a] = searchsorted(cdf_row_i, u[b,i,a]) clamped; -1 where a >= x[b,i]
// RNG: jax_threefry_partitionable=True stream:
//   bits[i] = o0 ^ o1, (o0,o1) = threefry2x32(key=(0,42), counter=(0, i))
//   u = bitcast((bits>>9)|0x3f800000) - 1.0f
// Search: unnormalized cumsum, target u*total; interpolation-start window
// +-64, verified bracket, exact full-range fallback (round 11).
//
// Round 14 = R12 core (padded scalar cdf writes, reg diet, interp search)
// + the never-tested combo: 2 ROWS PER BLOCK WITH REGISTER PREFETCH under
// the <=64-VGPR diet. 2048 blocks (one generation at 8 blocks/CU): row1's
// 4 global_load_dwordx4 issue in the PROLOGUE and stay in flight (compiler
// vmcnt tracks a-regs vs b-regs) while row0 builds+searches its cdf ->
// HBM never idles behind the compute convoy. R5 tested this idea but with
// loc[16]+bucket-search pushing VGPR>64 (occupancy halved, gain cancelled);
// the R12 diet keeps peak live ~60 VGPR.

#define N_IN    4096
#define N_OUT   4096
#define BS      32
#define MAX_A   16
#define THREADS 256
#define HALF    1048576u  /* 16 * N_IN * MAX_A */
#define WIN     64        /* half-width of interpolation window */
#define GRID    (N_IN / 2)

// +1 word per 32: spreads strided access across banks (R12 layout)
__device__ __forceinline__ int padi(int j) { return j + (j >> 5); }

__device__ __forceinline__ uint32_t rotl32(uint32_t x, uint32_t r) {
    return (x << r) | (x >> (32u - r));
}

// Threefry-2x32, 20 rounds, key (0, 42) — jax.random.key(42)
__device__ __forceinline__ void threefry2x32_42(uint32_t x0, uint32_t x1,
                                                uint32_t& o0, uint32_t& o1) {
    const uint32_t k0 = 0u, k1 = 42u;
    const uint32_t k2 = k0 ^ k1 ^ 0x1BD11BDAu;
    x0 += k0; x1 += k1;
#define TF_R(r) { x0 += x1; x1 = rotl32(x1, (r)); x1 ^= x0; }
    TF_R(13) TF_R(15) TF_R(26) TF_R(6)
    x0 += k1; x1 += k2 + 1u;
    TF_R(17) TF_R(29) TF_R(16) TF_R(24)
    x0 += k2; x1 += k0 + 2u;
    TF_R(13) TF_R(15) TF_R(26) TF_R(6)
    x0 += k0; x1 += k1 + 3u;
    TF_R(17) TF_R(29) TF_R(16) TF_R(24)
    x0 += k1; x1 += k2 + 4u;
    TF_R(13) TF_R(15) TF_R(26) TF_R(6)
    x0 += k2; x1 += k0 + 5u;
#undef TF_R
    o0 = x0; o1 = x1;
}

__device__ __forceinline__ float bits_to_uniform(uint32_t b) {
    uint32_t f = (b >> 9) | 0x3f800000u;
    float r;
    __builtin_memcpy(&r, &f, 4);
    return r - 1.0f;
}

// one row's scan + cdf write + interp search + store, given staged regs
__device__ __forceinline__ void process_row(
        float* cdf, float* wsum, const int* xcr,
        float4 v0, float4 v1, float4 v2, float4 v3,
        int row, int t, int lane, int wid, int bb, int aa,
        uint32_t j0, float u0, float u1, int* __restrict__ out) {

    // per-thread total (no loc array)
    float s = 0.f;
    s += v0.x; s += v0.y; s += v0.z; s += v0.w;
    s += v1.x; s += v1.y; s += v1.z; s += v1.w;
    s += v2.x; s += v2.y; s += v2.z; s += v2.w;
    s += v3.x; s += v3.y; s += v3.z; s += v3.w;
    const float my_total = s;

    float incl = my_total;
    #pragma unroll
    for (int d = 1; d < 64; d <<= 1) {
        float n = __shfl_up(incl, d, 64);
        if (lane >= d) incl += n;
    }
    if (lane == 63) wsum[wid] = incl;
    __syncthreads();   // B1: wsum visible

    const float4 ws = *(const float4*)wsum;
    const float total = ws.x + ws.y + ws.z + ws.w;
    float wprefix = 0.f;
    if (wid > 0) wprefix += ws.x;
    if (wid > 1) wprefix += ws.y;
    if (wid > 2) wprefix += ws.z;
    const float chunk_prefix = wprefix + incl - my_total;

    // write cumsum: 16 scalar padded writes, running sum recomputed
    {
        const int base = t * 16;
        float r = chunk_prefix;
        r += v0.x; cdf[padi(base +  0)] = r;
        r += v0.y; cdf[padi(base +  1)] = r;
        r += v0.z; cdf[padi(base +  2)] = r;
        r += v0.w; cdf[padi(base +  3)] = r;
        r += v1.x; cdf[padi(base +  4)] = r;
        r += v1.y; cdf[padi(base +  5)] = r;
        r += v1.z; cdf[padi(base +  6)] = r;
        r += v1.w; cdf[padi(base +  7)] = r;
        r += v2.x; cdf[padi(base +  8)] = r;
        r += v2.y; cdf[padi(base +  9)] = r;
        r += v2.z; cdf[padi(base + 10)] = r;
        r += v2.w; cdf[padi(base + 11)] = r;
        r += v3.x; cdf[padi(base + 12)] = r;
        r += v3.y; cdf[padi(base + 13)] = r;
        r += v3.z; cdf[padi(base + 14)] = r;
        r += v3.w; cdf[padi(base + 15)] = r;
    }
    __syncthreads();   // B2: full cdf visible

    const float t0 = u0 * total;
    const float t1 = u1 * total;

    const int i0 = (int)(u0 * (float)N_OUT);
    const int i1 = (int)(u1 * (float)N_OUT);
    int lo0 = i0 - WIN; if (lo0 < 0) lo0 = 0;
    int hi0 = i0 + WIN; if (hi0 > N_OUT) hi0 = N_OUT;
    int lo1 = i1 - WIN; if (lo1 < 0) lo1 = 0;
    int hi1 = i1 + WIN; if (hi1 > N_OUT) hi1 = N_OUT;

    const bool ok0 = (lo0 == 0     || cdf[padi(lo0 - 1)] <  t0) &&
                     (hi0 == N_OUT || cdf[padi(hi0 - 1)] >= t0);
    const bool ok1 = (lo1 == 0     || cdf[padi(lo1 - 1)] <  t1) &&
                     (hi1 == N_OUT || cdf[padi(hi1 - 1)] >= t1);

    if (ok0 && ok1) {
        #pragma unroll
        for (int it = 0; it < 7; ++it) {
            const int m0 = (lo0 + hi0) >> 1;
            const int m1 = (lo1 + hi1) >> 1;
            const float f0 = cdf[padi(m0)];
            const float f1 = cdf[padi(m1)];
            if (f0 < t0) lo0 = m0 + 1; else hi0 = m0;
            if (f1 < t1) lo1 = m1 + 1; else hi1 = m1;
        }
    } else {
        lo0 = 0; hi0 = N_OUT; lo1 = 0; hi1 = N_OUT;
        #pragma unroll
        for (int it = 0; it < 12; ++it) {
            const int m0 = (lo0 + hi0) >> 1;
            const int m1 = (lo1 + hi1) >> 1;
            const float f0 = cdf[padi(m0)];
            const float f1 = cdf[padi(m1)];
            if (f0 < t0) lo0 = m0 + 1; else hi0 = m0;
            if (f1 < t1) lo1 = m1 + 1; else hi1 = m1;
        }
    }
    const int idx0 = lo0 < N_OUT ? lo0 : N_OUT - 1;
    const int idx1 = lo1 < N_OUT ? lo1 : N_OUT - 1;

    out[j0]        = (aa < xcr[bb])      ? idx0 : -1;
    out[j0 + HALF] = (aa < xcr[bb + 16]) ? idx1 : -1;
}

__global__ __launch_bounds__(THREADS, 8)
void aco_sample_kernel(const int* __restrict__ x,
                       const float* __restrict__ w,
                       int* __restrict__ out) {
    __shared__ float cdf[N_OUT + (N_OUT >> 5)];  // +1/32 padded, reused per row
    __shared__ float wsum[4];
    __shared__ int   xc[2][BS];

    const int t    = threadIdx.x;
    const int lane = t & 63;
    const int wid  = t >> 6;
    const int bb   = t >> 4;
    const int aa   = t & 15;
    const int row0 = blockIdx.x;
    const int row1 = blockIdx.x + GRID;

    // ---- prologue: issue BOTH rows' loads (8x dwordx4 in flight) ----
    const float4* wr0 = (const float4*)(w + (size_t)row0 * N_OUT);
    float4 a0 = wr0[t * 4 + 0];
    float4 a1 = wr0[t * 4 + 1];
    float4 a2 = wr0[t * 4 + 2];
    float4 a3 = wr0[t * 4 + 3];
    const float4* wr1 = (const float4*)(w + (size_t)row1 * N_OUT);
    float4 b0 = wr1[t * 4 + 0];
    float4 b1 = wr1[t * 4 + 1];
    float4 b2 = wr1[t * 4 + 2];
    float4 b3 = wr1[t * 4 + 3];

    if (t < BS)          xc[0][t]      = x[t * N_IN + row0];
    else if (t < 2 * BS) xc[1][t - BS] = x[(t - BS) * N_IN + row1];

    // ---- threefry row0 in the load shadow ----
    const uint32_t jA = (uint32_t)(bb * (N_IN * MAX_A) + row0 * MAX_A + aa);
    uint32_t o0, o1, p0, p1;
    threefry2x32_42(0u, jA, o0, o1);
    threefry2x32_42(0u, jA + HALF, p0, p1);
    const float uA0 = bits_to_uniform(o0 ^ o1);
    const float uA1 = bits_to_uniform(p0 ^ p1);

    // ---- row 0 (waits on a-regs only; b-loads stay in flight) ----
    process_row(cdf, wsum, xc[0], a0, a1, a2, a3,
                row0, t, lane, wid, bb, aa, jA, uA0, uA1, out);

    // threefry row1 (runs while other waves still search row0)
    const uint32_t jB = (uint32_t)(bb * (N_IN * MAX_A) + row1 * MAX_A + aa);
    threefry2x32_42(0u, jB, o0, o1);
    threefry2x32_42(0u, jB + HALF, p0, p1);
    const float uB0 = bits_to_uniform(o0 ^ o1);
    const float uB1 = bits_to_uniform(p0 ^ p1);

    __syncthreads();   // B3: all waves done reading row0's cdf

    // ---- row 1 ----
    process_row(cdf, wsum, xc[1], b0, b1, b2, b3,
                row1, t, lane, wid, bb, aa, jB, uB0, uB1, out);
}

extern "C" void kernel_launch(void* const* d_in, const int* in_sizes, int n_in,
                              void* d_out, int out_size, void* d_ws, size_t ws_size,
                              hipStream_t stream) {
    // select inputs by size (robust to ordering):
    //   x: 32*4096 int32; weights: 4096*4096 f32
    const int*   x;
    const float* w;
    if (in_sizes[0] == BS * N_IN) { x = (const int*)d_in[0]; w = (const float*)d_in[1]; }
    else                          { x = (const int*)d_in[1]; w = (const float*)d_in[0]; }
    aco_sample_kernel<<<GRID, THREADS, 0, stream>>>(x, w, (int*)d_out);
}